// Round 17
// baseline (3912.461 us; speedup 1.0000x reference)
//
#include <hip/hip_runtime.h>
#include <hip/hip_bf16.h>

#define T_STEPS 2048
#define BATCH   1024
#define NUNITS  128
#define LOG2E   1.4426950408889634f

typedef __attribute__((ext_vector_type(2))) int    i32x2;
typedef __attribute__((ext_vector_type(4))) int    int4v;

__device__ __forceinline__ float sigm_pre(float xs) {
    return __builtin_amdgcn_rcpf(1.0f + __builtin_amdgcn_exp2f(-xs));
}
__device__ __forceinline__ float tanh_pre(float xs) {
    return fmaf(-2.0f, __builtin_amdgcn_rcpf(1.0f + __builtin_amdgcn_exp2f(xs)), 1.0f);
}
// lanes 0-31 = a[self], lanes 32-63 = b[lane-32]  (verified R7)
__device__ __forceinline__ int swap_lo_i(int a, int b) {
    i32x2 r = __builtin_amdgcn_permlane32_swap(a, b, false, false);
    return r[0];
}
// (lane&16)==0 -> a[self], ==1 -> b[lane-16]  (verified R15)
__device__ __forceinline__ int swap16_lo_i(int a, int b) {
    i32x2 r = __builtin_amdgcn_permlane16_swap(a, b, false, false);
    return r[0];
}

// ---------------- embedding pre-pass: e[t][b][0..23] = rint(sigmoid(.)*127) i8,
// bytes 24-31 zero pad (verified R13)
__global__ __launch_bounds__(256) void emb_kernel(const float* __restrict__ x,
                                                  const float* __restrict__ Wemb,
                                                  const float* __restrict__ bemb,
                                                  uchar* __restrict__ e_out) {
    int g = blockIdx.x * 256 + threadIdx.x;   // g = t*1024 + b
    int t = g >> 10;
    int b = g & 1023;
    const float* xr = x + ((size_t)b * T_STEPS + t) * 64;

    float4 xv[16];
#pragma unroll
    for (int i = 0; i < 16; i++) xv[i] = ((const float4*)xr)[i];

    float acc[24];
#pragma unroll
    for (int j = 0; j < 24; j++) acc[j] = bemb[j];

#pragma unroll
    for (int d = 0; d < 64; d++) {
        float xs = ((const float*)xv)[d];
#pragma unroll
        for (int j = 0; j < 24; j++) acc[j] = fmaf(xs, Wemb[d * 24 + j], acc[j]);
    }

    uint outp[8] = {0, 0, 0, 0, 0, 0, 0, 0};
#pragma unroll
    for (int j = 0; j < 24; j++) {
        float s = __builtin_amdgcn_rcpf(1.0f + __builtin_amdgcn_exp2f(-LOG2E * acc[j]));
        int q = (int)__builtin_rintf(s * 127.0f);
        outp[j >> 2] |= (uint)(q & 255) << (8 * (j & 3));
    }
    uint4* dst = (uint4*)(e_out + (size_t)g * 32);
    dst[0] = ((const uint4*)outp)[0];
    dst[1] = ((const uint4*)outp)[1];
}

// ---------------- recurrent kernel: 1024 blocks x 64 threads = 1 WAVE per block,
// 1 batch row per block, ALL 128 units wave-resident -> ZERO barriers.
// Per step: 96 i8-MFMAs (8 unit-tiles x 4 gates x K=192), per-gate distribution via
// permlane32/16 swaps -> 2 cells/lane, gate math, 2 ds_write_b8, lgkmcnt(0) only
// (intra-wave fence; the 8-wave barrier convoy of R3..R16 is eliminated).
// W: int8 per-(gate,unit) scaled, wq[8][4][3] = 384 regs -> relies on the gfx950
// unified 512-reg VGPR/AGPR file (write-once, MFMA-read-only).
__global__ __launch_bounds__(64) void lstm_kernel(
    const uchar* __restrict__ e_ws,
    const float* __restrict__ Wf, const float* __restrict__ bf_,
    const float* __restrict__ Wi, const float* __restrict__ bi_,
    const float* __restrict__ Wg, const float* __restrict__ bg_,
    const float* __restrict__ Wo, const float* __restrict__ bo_,
    const float* __restrict__ Wout, const float* __restrict__ bout,
    float* __restrict__ out) {
    __shared__ __align__(16) char zq[2][4][16][16];   // [ks2][kslot4][row16][16B] = 2 KiB

    const int lane = threadIdx.x & 63;
    const int l15  = lane & 15;
    const int kg   = lane >> 4;     // B/A k-group; also distribution lane-group
    const int r0   = blockIdx.x;    // this block's single batch row

    const float* Wp[4] = {Wf, Wi, Wg, Wo};
    const float* Bp[4] = {bf_, bi_, bg_, bo_};
    const float gsc[4] = {LOG2E, LOG2E, 2.0f * LOG2E, LOG2E};

    // owned cells after distribution: units ua = Ta*16+l15, ub = Tb*16+l15
    const int Ta = (kg & 1) + ((kg >> 1) << 2);   // [0,1,4,5][kg]
    const int Tb = Ta + 2;                         // [2,3,6,7][kg]
    const int ua = Ta * 16 + l15, ub = Tb * 16 + l15;

    // ---- pack W: per-(gate,unit) scaled i8; lane holds B-cols for units T*16+l15
    int4v wq[8][4][3];
#pragma unroll
    for (int T = 0; T < 8; T++) {
        const int ucol = T * 16 + l15;
#pragma unroll
        for (int gt = 0; gt < 4; gt++) {
            float amax = 1e-20f;
            for (int k = 0; k < 152; k++) {
                float v = (k < 128) ? Wp[gt][(24 + k) * NUNITS + ucol]
                                    : Wp[gt][(k - 128) * NUNITS + ucol];
                amax = fmaxf(amax, fabsf(v * gsc[gt]));
            }
            float isq = 127.0f / amax;
#pragma unroll
            for (int ks = 0; ks < 3; ks++) {
#pragma unroll
                for (int w = 0; w < 4; w++) {
                    int word = 0;
#pragma unroll
                    for (int b = 0; b < 4; b++) {
                        int k = ks * 64 + kg * 16 + w * 4 + b;
                        float v = 0.0f;
                        if (k < 128) v = Wp[gt][(24 + k) * NUNITS + ucol] * gsc[gt];
                        else if (k < 152) v = Wp[gt][(k - 128) * NUNITS + ucol] * gsc[gt];
                        int q = (int)__builtin_rintf(v * isq);
                        word |= (q & 255) << (8 * b);
                    }
                    wq[T][gt][ks][w] = word;
                }
            }
        }
    }
    // dequant factor + bias for the 2 OWNED units (same amax formula as the pack)
    float fct_a[4], fct_b[4], bias_a[4], bias_b[4];
#pragma unroll
    for (int gt = 0; gt < 4; gt++) {
        float ama = 1e-20f, amb = 1e-20f;
        for (int k = 0; k < 152; k++) {
            float va = (k < 128) ? Wp[gt][(24 + k) * NUNITS + ua]
                                 : Wp[gt][(k - 128) * NUNITS + ua];
            float vb = (k < 128) ? Wp[gt][(24 + k) * NUNITS + ub]
                                 : Wp[gt][(k - 128) * NUNITS + ub];
            ama = fmaxf(ama, fabsf(va * gsc[gt]));
            amb = fmaxf(amb, fabsf(vb * gsc[gt]));
        }
        fct_a[gt] = ama * (1.0f / 16129.0f);
        fct_b[gt] = amb * (1.0f / 16129.0f);
        bias_a[gt] = Bp[gt][ua] * gsc[gt];
        bias_b[gt] = Bp[gt][ub] * gsc[gt];
    }
    const int4v zeroi = {0, 0, 0, 0};

    // zero z buffer (h0 = 0; rows 1-15 stay zero forever)
    for (int i = lane; i < (int)(sizeof(zq) / 4); i += 64) ((int*)zq)[i] = 0;

    // addrs: A-frag read 16B (row l15, k = ks*64+kg*16+j); 2 owned-cell writes (row 0)
    const char* zr0 = &zq[0][kg][l15][0];
    const char* zr1 = &zq[1][kg][l15][0];
    char* wa = &zq[ua >> 6][(ua >> 4) & 3][0][ua & 15];
    char* wb = &zq[ub >> 6][(ub >> 4) & 3][0][ub & 15];

    // ---- e ring depth 2: lanes (kg<2, l15==0): row 0, bytes kg*16..+16
    const uchar* elbase = e_ws + ((size_t)r0 * 32 + kg * 16);
    const bool eload = (kg < 2) && (l15 == 0);
    int4v e0 = zeroi, e1 = zeroi;
    if (eload) {
        e0 = *(const int4v*)(const void*)(elbase);
        e1 = *(const int4v*)(const void*)(elbase + 32768);   // t=1 (1024*32 B/step)
    }
    const uchar* eptr = elbase + 2 * 32768;

    __syncthreads();   // single wave; cheap. Covers the zero-init.

    float ca = 0.0f, cb = 0.0f;

    auto STEP = [&](int4v& ecur) {
        int4v z0 = *(const int4v*)(const void*)(zr0);   // h units 0-63
        int4v z1 = *(const int4v*)(const void*)(zr1);   // h units 64-127

        float gA[4], gB[4];
#pragma unroll
        for (int gt = 0; gt < 4; gt++) {
            int4v acc[8];
#pragma unroll
            for (int T = 0; T < 8; T++)
                acc[T] = __builtin_amdgcn_mfma_i32_16x16x64_i8(ecur, wq[T][gt][2], zeroi, 0, 0, 0);
#pragma unroll
            for (int T = 0; T < 8; T++)
                acc[T] = __builtin_amdgcn_mfma_i32_16x16x64_i8(z0, wq[T][gt][0], acc[T], 0, 0, 0);
#pragma unroll
            for (int T = 0; T < 8; T++)
                acc[T] = __builtin_amdgcn_mfma_i32_16x16x64_i8(z1, wq[T][gt][1], acc[T], 0, 0, 0);

            // distribute row-0 results: tiles 4-7 -> lanes 32-63, then odd tile of
            // each pair -> lane-group+16. Lane(kg,l15) ends owning units ua, ub.
            int s0 = swap_lo_i(acc[0][0], acc[4][0]);
            int s1 = swap_lo_i(acc[1][0], acc[5][0]);
            int s2 = swap_lo_i(acc[2][0], acc[6][0]);
            int s3 = swap_lo_i(acc[3][0], acc[7][0]);
            int va = swap16_lo_i(s0, s1);   // tiles [0,1,4,5][kg]
            int vb = swap16_lo_i(s2, s3);   // tiles [2,3,6,7][kg]
            gA[gt] = fmaf((float)va, fct_a[gt], bias_a[gt]);
            gB[gt] = fmaf((float)vb, fct_b[gt], bias_b[gt]);
        }

        // refill e with e(t+2): marching pointer (<=2-step overrun, never consumed)
        if (eload) ecur = *(const int4v*)(const void*)(eptr);
        eptr += 32768;

        float fga = sigm_pre(gA[0]), fgb = sigm_pre(gB[0]);
        float iga = sigm_pre(gA[1]), igb = sigm_pre(gB[1]);
        float gga = tanh_pre(gA[2]), ggb = tanh_pre(gB[2]);
        float oga = sigm_pre(gA[3]), ogb = sigm_pre(gB[3]);
        ca = fmaf(ca, fga, iga * gga);
        cb = fmaf(cb, fgb, igb * ggb);
        float ha = tanh_pre(2.0f * LOG2E * ca) * oga;
        float hb = tanh_pre(2.0f * LOG2E * cb) * ogb;

        // quantize (RNE via rint) and store the wave's 128 h bytes
        *wa = (char)(int)__builtin_rintf(ha * 127.0f);
        *wb = (char)(int)__builtin_rintf(hb * 127.0f);

        // intra-wave fence only — NO s_barrier anywhere in the loop
        asm volatile("s_waitcnt lgkmcnt(0)" ::: "memory");
        __builtin_amdgcn_sched_barrier(0);
    };

    for (int t = 0; t < T_STEPS; t += 2) {
        STEP(e0);
        STEP(e1);
    }

    // h_last (i8, row 0) -> output scalar
    if (lane == 0) {
        float s2 = 0.0f;
#pragma unroll
        for (int k = 0; k < NUNITS; k++)
            s2 += (float)zq[k >> 6][(k >> 4) & 3][0][k & 15] * Wout[k];
        float s = s2 * (1.0f / 127.0f) + bout[0];
        out[r0] = __builtin_amdgcn_rcpf(1.0f + __builtin_amdgcn_exp2f(-LOG2E * s));
    }
}

extern "C" void kernel_launch(void* const* d_in, const int* in_sizes, int n_in,
                              void* d_out, int out_size, void* d_ws, size_t ws_size,
                              hipStream_t stream) {
    const float* x     = (const float*)d_in[0];
    const float* Wemb  = (const float*)d_in[1];
    const float* bemb  = (const float*)d_in[2];
    const float* Wf    = (const float*)d_in[3];
    const float* bf_   = (const float*)d_in[4];
    const float* Wi    = (const float*)d_in[5];
    const float* bi_   = (const float*)d_in[6];
    const float* Wg    = (const float*)d_in[7];
    const float* bg_   = (const float*)d_in[8];
    const float* Wo    = (const float*)d_in[9];
    const float* bo_   = (const float*)d_in[10];
    const float* Wout  = (const float*)d_in[11];
    const float* bout  = (const float*)d_in[12];
    float* out = (float*)d_out;
    uchar* e_ws = (uchar*)d_ws;   // [T][B][32] i8, 64 MB (+<=64KB overrun reads)

    int nrows = BATCH * T_STEPS;
    emb_kernel<<<nrows / 256, 256, 0, stream>>>(x, Wemb, bemb, e_ws);
    lstm_kernel<<<BATCH, 64, 0, stream>>>(e_ws, Wf, bf_, Wi, bi_, Wg, bg_,
                                          Wo, bo_, Wout, bout, out);
}

// Round 18
// 1212.912 us; speedup vs baseline: 3.2257x; 3.2257x over previous
//
#include <hip/hip_runtime.h>
#include <hip/hip_bf16.h>

#define T_STEPS 2048
#define BATCH   1024
#define NUNITS  128
#define ROWS    4
#define LOG2E   1.4426950408889634f

typedef __attribute__((ext_vector_type(4))) float  f32x4;
typedef __attribute__((ext_vector_type(2))) int    i32x2;
typedef __attribute__((ext_vector_type(4))) int    int4v;

__device__ __forceinline__ float sigm_pre(float xs) {
    return __builtin_amdgcn_rcpf(1.0f + __builtin_amdgcn_exp2f(-xs));
}
__device__ __forceinline__ float tanh_pre(float xs) {
    return fmaf(-2.0f, __builtin_amdgcn_rcpf(1.0f + __builtin_amdgcn_exp2f(xs)), 1.0f);
}
// lanes 0-31 = a[self], lanes 32-63 = b[lane-32]  (verified R7); int version
__device__ __forceinline__ int swap_lo_i(int a, int b) {
    i32x2 r = __builtin_amdgcn_permlane32_swap(a, b, false, false);
    return r[0];
}
// 16-lane-granular analog (verified R15): (lane&16)==0 -> a[self], ==1 -> b[lane-16]
__device__ __forceinline__ int swap16_lo_i(int a, int b) {
    i32x2 r = __builtin_amdgcn_permlane16_swap(a, b, false, false);
    return r[0];
}

// ---------------- embedding pre-pass: e[t][b][0..23] = rint(sigmoid(.)*127) as i8,
// bytes 24-31 zero pad (verified R13)
__global__ __launch_bounds__(256) void emb_kernel(const float* __restrict__ x,
                                                  const float* __restrict__ Wemb,
                                                  const float* __restrict__ bemb,
                                                  uchar* __restrict__ e_out) {
    int g = blockIdx.x * 256 + threadIdx.x;   // g = t*1024 + b
    int t = g >> 10;
    int b = g & 1023;
    const float* xr = x + ((size_t)b * T_STEPS + t) * 64;

    float4 xv[16];
#pragma unroll
    for (int i = 0; i < 16; i++) xv[i] = ((const float4*)xr)[i];

    float acc[24];
#pragma unroll
    for (int j = 0; j < 24; j++) acc[j] = bemb[j];

#pragma unroll
    for (int d = 0; d < 64; d++) {
        float xs = ((const float*)xv)[d];
#pragma unroll
        for (int j = 0; j < 24; j++) acc[j] = fmaf(xs, Wemb[d * 24 + j], acc[j]);
    }

    uint outp[8] = {0, 0, 0, 0, 0, 0, 0, 0};
#pragma unroll
    for (int j = 0; j < 24; j++) {
        float s = __builtin_amdgcn_rcpf(1.0f + __builtin_amdgcn_exp2f(-LOG2E * acc[j]));
        int q = (int)__builtin_rintf(s * 127.0f);
        outp[j >> 2] |= (uint)(q & 255) << (8 * (j & 3));
    }
    uint4* dst = (uint4*)(e_out + (size_t)g * 32);
    dst[0] = ((const uint4*)outp)[0];
    dst[1] = ((const uint4*)outp)[1];
}

// ---------------- recurrent kernel: 256 blocks x 512 threads (8 waves), 4 rows/block.
// All-INT8 GEMM (mfma_i32_16x16x64_i8, K=192 = h|e|pad), 1 valid cell/thread,
// all-VALU compaction (permlane32_swap pair + permlane16_swap), marching e-pointer.
// This is the verified R15 optimum (1134us lstm): balanced per-CU MFMA (96 instr
// ~490cyc) / VALU (~750cyc/SIMD incl. 10 trans/cell) / LDS (~150cyc) + the
// mandatory per-step barrier. R5/R8/R9/R10/R16/R17 all measured worse structures.
__global__ __launch_bounds__(512, 1) void lstm_kernel(
    const uchar* __restrict__ e_ws,
    const float* __restrict__ Wf, const float* __restrict__ bf_,
    const float* __restrict__ Wi, const float* __restrict__ bi_,
    const float* __restrict__ Wg, const float* __restrict__ bg_,
    const float* __restrict__ Wo, const float* __restrict__ bo_,
    const float* __restrict__ Wout, const float* __restrict__ bout,
    float* __restrict__ out) {
    __shared__ __align__(16) char zq[2][2][4][16][16];   // [P][ks2][kg4][row16][16B] = 4 KiB

    const int tid  = threadIdx.x;
    const int lane = tid & 63;
    const int wv   = tid >> 6;      // 0..7 -> unit tile [16wv,16wv+16)
    const int l15  = lane & 15;
    const int kg   = lane >> 4;     // 0..3 (A k-group; also this thread's OWNED ROW)
    const int r0   = blockIdx.x * ROWS;

    const float* Wp[4] = {Wf, Wi, Wg, Wo};
    const float* Bp[4] = {bf_, bi_, bg_, bo_};
    const float gsc[4] = {LOG2E, LOG2E, 2.0f * LOG2E, LOG2E};
    const int ucol = wv * 16 + l15;   // this lane's unit (D n-index)

    // ---- weights: per-(gate,unit) scaled int8 over all 152 K-rows, packed [gt][ks3]
    int4v wq[4][3];
    float fct[4], biasv[4];
#pragma unroll
    for (int gt = 0; gt < 4; gt++) {
        float amax = 1e-20f;
        for (int k = 0; k < 152; k++) {
            float v = (k < 128) ? Wp[gt][(24 + k) * NUNITS + ucol]
                                : Wp[gt][(k - 128) * NUNITS + ucol];
            amax = fmaxf(amax, fabsf(v * gsc[gt]));
        }
        float isq = 127.0f / amax;
        fct[gt] = amax * (1.0f / 16129.0f);   // s_w/127: i32 -> pre-activation scale
#pragma unroll
        for (int ks = 0; ks < 3; ks++) {
#pragma unroll
            for (int w = 0; w < 4; w++) {
                int word = 0;
#pragma unroll
                for (int b = 0; b < 4; b++) {
                    int k = ks * 64 + kg * 16 + w * 4 + b;
                    float v = 0.0f;
                    if (k < 128) v = Wp[gt][(24 + k) * NUNITS + ucol] * gsc[gt];
                    else if (k < 152) v = Wp[gt][(k - 128) * NUNITS + ucol] * gsc[gt];
                    int q = (int)__builtin_rintf(v * isq);
                    word |= (q & 255) << (8 * b);
                }
                wq[gt][ks][w] = word;
            }
        }
        biasv[gt] = Bp[gt][ucol] * gsc[gt];
    }
    const int4v zeroi = {0, 0, 0, 0};

    // zero both z buffers (h0 = 0; rows 4-15 stay zero forever)
    for (int i = tid; i < (int)(sizeof(zq) / 4); i += 512) ((int*)zq)[i] = 0;

    // LDS addrs: A-frag read 16B (k = ks*64 + kg*16 + j); write 1 i8 cell (row=kg)
    const char* zrd = &zq[0][0][kg][l15][0];            // + P*2048 + ks*1024
    char* zwr = &zq[0][ucol >> 6][(ucol >> 4) & 3][kg][ucol & 15];

    // ---- e ring, depth 2: lanes (kg<2, l15<4) hold row l15, bytes kg*16..+16
    const uchar* elbase = e_ws + ((size_t)(r0 + (l15 & 3)) * 32 + kg * 16);
    const bool eload = (kg < 2) && (l15 < 4);
    int4v e0 = zeroi, e1 = zeroi;
    if (eload) {
        e0 = *(const int4v*)(const void*)(elbase);
        e1 = *(const int4v*)(const void*)(elbase + 32768);   // t=1 (1024*32 B/step)
    }
    const uchar* eptr = elbase + 2 * 32768;   // marching prefetch ptr: next load = e(2)

    __syncthreads();

    float c0 = 0.0f;

    auto STEP = [&](int P, int4v& ecur) {
        // e-slice MFMA first: register A-operand, overlaps the z ds_read latency
        int4v acc[4];
#pragma unroll
        for (int gt = 0; gt < 4; gt++)
            acc[gt] = __builtin_amdgcn_mfma_i32_16x16x64_i8(ecur, wq[gt][2], zeroi, 0, 0, 0);

        const char* zb = zrd + P * 2048;
        int4v z0 = *(const int4v*)(const void*)(zb);          // k 0-63
        int4v z1 = *(const int4v*)(const void*)(zb + 1024);   // k 64-127
#pragma unroll
        for (int gt = 0; gt < 4; gt++)
            acc[gt] = __builtin_amdgcn_mfma_i32_16x16x64_i8(z0, wq[gt][0], acc[gt], 0, 0, 0);
#pragma unroll
        for (int gt = 0; gt < 4; gt++)
            acc[gt] = __builtin_amdgcn_mfma_i32_16x16x64_i8(z1, wq[gt][1], acc[gt], 0, 0, 0);

        // refill ering with e(t+2): unconditional marching pointer (<=2-step overrun
        // into the >=96MB workspace; overrun loads never consumed)
        if (eload) ecur = *(const int4v*)(const void*)(eptr);
        eptr += 32768;

        // full compaction (i32, bit-exact, all-VALU): swap32 pair then swap16 ->
        // lane-group kg owns row kg of unit ucol
        float g[4];
#pragma unroll
        for (int gt = 0; gt < 4; gt++) {
            int a0 = swap_lo_i(acc[gt][0], acc[gt][2]);    // l0-15:r0, l32-47:r2
            int a1 = swap_lo_i(acc[gt][1], acc[gt][3]);    // l0-15:r1, l32-47:r3
            int sel = swap16_lo_i(a0, a1);                 // lane-group kg -> row kg
            g[gt] = fmaf((float)sel, fct[gt], biasv[gt]);
        }

        float fg = sigm_pre(g[0]);
        float ig = sigm_pre(g[1]);
        float gg = tanh_pre(g[2]);
        float og = sigm_pre(g[3]);
        c0 = fmaf(c0, fg, ig * gg);
        float h0 = tanh_pre(2.0f * LOG2E * c0) * og;

        // quantize h (|h|<1 strictly); every lane writes its 1 cell (row kg)
        int q0i = (int)__builtin_rintf(h0 * 127.0f);
        *(zwr + ((P ^ 1) * 2048)) = (char)q0i;

        asm volatile("s_waitcnt lgkmcnt(0)" ::: "memory");
        __builtin_amdgcn_s_barrier();
        __builtin_amdgcn_sched_barrier(0);
    };

    for (int t = 0; t < T_STEPS; t += 2) {
        STEP(0, e0);
        STEP(1, e1);
    }

    // h_last (i8) in buffer 0, rows 0-3
    if (tid < ROWS) {
        float s2 = 0.0f;
#pragma unroll
        for (int k = 0; k < NUNITS; k++)
            s2 += (float)zq[0][k >> 6][(k >> 4) & 3][tid][k & 15] * Wout[k];
        float s = s2 * (1.0f / 127.0f) + bout[0];
        out[r0 + tid] = __builtin_amdgcn_rcpf(1.0f + __builtin_amdgcn_exp2f(-LOG2E * s));
    }
}

extern "C" void kernel_launch(void* const* d_in, const int* in_sizes, int n_in,
                              void* d_out, int out_size, void* d_ws, size_t ws_size,
                              hipStream_t stream) {
    const float* x     = (const float*)d_in[0];
    const float* Wemb  = (const float*)d_in[1];
    const float* bemb  = (const float*)d_in[2];
    const float* Wf    = (const float*)d_in[3];
    const float* bf_   = (const float*)d_in[4];
    const float* Wi    = (const float*)d_in[5];
    const float* bi_   = (const float*)d_in[6];
    const float* Wg    = (const float*)d_in[7];
    const float* bg_   = (const float*)d_in[8];
    const float* Wo    = (const float*)d_in[9];
    const float* bo_   = (const float*)d_in[10];
    const float* Wout  = (const float*)d_in[11];
    const float* bout  = (const float*)d_in[12];
    float* out = (float*)d_out;
    uchar* e_ws = (uchar*)d_ws;   // [T][B][32] i8, 64 MB (+<=64KB overrun reads)

    int nrows = BATCH * T_STEPS;
    emb_kernel<<<nrows / 256, 256, 0, stream>>>(x, Wemb, bemb, e_ws);
    lstm_kernel<<<BATCH / ROWS, 512, 0, stream>>>(e_ws, Wf, bf_, Wi, bi_, Wg, bg_,
                                                  Wo, bo_, Wout, bout, out);
}